// Round 1
// baseline (1237.616 us; speedup 1.0000x reference)
//
#include <hip/hip_runtime.h>

namespace {

constexpr int Bn = 2;
constexpr int Dn = 64;
constexpr int Hn = 96;
constexpr int Wn = 96;
constexpr int HW = Hn * Wn;          // 9216
constexpr int S  = Dn * HW;          // 589824
constexpr int NBS = Bn * S;          // 1179648  (one stacked-volume's elems per "volume" slot)
constexpr int NT  = 2 * NBS;         // 2359296  (vol0 = pred, vol1 = truth)
constexpr float INFD = 1e12f;
constexpr float EPSf = 1e-7f;
constexpr int TPB = 256;
constexpr int BLK_NT  = NT  / TPB;   // 9216
constexpr int BLK_NBS = NBS / TPB;   // 4608
constexpr int BLK_PER_VB = S / TPB;  // 2304 blocks per (volume,batch) slab in NT-kernels
constexpr int NITER = 10;

__device__ __forceinline__ void decomp(int idx, int& z, int& y, int& x) {
  int s = idx % S;
  z = s / HW;
  int r = s - z * HW;
  y = r / Wn;
  x = r - y * Wn;
}

__global__ __launch_bounds__(64) void k_init_small(double* sums, unsigned* rmax) {
  int t = threadIdx.x;
  if (t < 4) { sums[t] = 0.0; rmax[t] = 0u; }
}

// binarize both masks AND write the EDT d2 init (fused)
__global__ __launch_bounds__(TPB) void k_binarize(const float* __restrict__ logits,
                                                  const int* __restrict__ labels,
                                                  float* __restrict__ M,
                                                  float* __restrict__ D2) {
  int idx = blockIdx.x * TPB + threadIdx.x;     // over NBS
  if (idx >= NBS) return;
  int b = idx / S;
  int s = idx - b * S;
  float l0 = logits[(b * 2 + 0) * S + s];
  float l1 = logits[(b * 2 + 1) * S + s];
  float vp = (l1 > l0) ? 1.0f : 0.0f;           // softmax(prob1)>0.5 <=> l1>l0
  float vt = (labels[idx] > 0) ? 1.0f : 0.0f;
  M[idx]        = vp;
  M[NBS + idx]  = vt;
  D2[idx]       = (vp > 0.0f) ? INFD : 0.0f;
  D2[NBS + idx] = (vt > 0.0f) ? INFD : 0.0f;
}

// soft_erode: min over {center, z±1, y±1, x±1}, out-of-bounds skipped (+inf pad)
__global__ __launch_bounds__(TPB) void k_erode(const float* __restrict__ in,
                                               float* __restrict__ out) {
  int idx = blockIdx.x * TPB + threadIdx.x;     // over NT
  if (idx >= NT) return;
  int z, y, x; decomp(idx, z, y, x);
  float v = in[idx];
  if (z > 0)      v = fminf(v, in[idx - HW]);
  if (z < Dn - 1) v = fminf(v, in[idx + HW]);
  if (y > 0)      v = fminf(v, in[idx - Wn]);
  if (y < Hn - 1) v = fminf(v, in[idx + Wn]);
  if (x > 0)      v = fminf(v, in[idx - 1]);
  if (x < Wn - 1) v = fminf(v, in[idx + 1]);
  out[idx] = v;
}

// 1-axis maxpool window 3 (separable factor of the 3x3x3 dilation), -inf pad
template <int AXIS>
__global__ __launch_bounds__(TPB) void k_dil(const float* __restrict__ in,
                                             float* __restrict__ out) {
  int idx = blockIdx.x * TPB + threadIdx.x;     // over NT
  if (idx >= NT) return;
  int z, y, x; decomp(idx, z, y, x);
  int i, L, stride;
  if constexpr (AXIS == 0) { i = z; L = Dn; stride = HW; }
  else if constexpr (AXIS == 1) { i = y; L = Hn; stride = Wn; }
  else { i = x; L = Wn; stride = 1; }
  float v = in[idx];
  if (i > 0)     v = fmaxf(v, in[idx - stride]);
  if (i < L - 1) v = fmaxf(v, in[idx + stride]);
  out[idx] = v;
}

// skel = relu(x - open)  (binary: x && !open)
__global__ __launch_bounds__(TPB) void k_skel_init(const float* __restrict__ x,
                                                   const float* __restrict__ open_,
                                                   float* __restrict__ skel) {
  int idx = blockIdx.x * TPB + threadIdx.x;
  if (idx >= NT) return;
  skel[idx] = (x[idx] != 0.0f && open_[idx] == 0.0f) ? 1.0f : 0.0f;
}

// skel |= (x_new && !open)
__global__ __launch_bounds__(TPB) void k_skel_upd(const float* __restrict__ xn,
                                                  const float* __restrict__ open_,
                                                  float* __restrict__ skel) {
  int idx = blockIdx.x * TPB + threadIdx.x;
  if (idx >= NT) return;
  float d = (xn[idx] != 0.0f && open_[idx] == 0.0f) ? 1.0f : 0.0f;
  skel[idx] = (skel[idx] != 0.0f || d != 0.0f) ? 1.0f : 0.0f;
}

// one EDT axis pass: out[i] = min_j (i-j)^2 + in[j]  (exact f32 match to reference)
template <int AXIS>
__global__ __launch_bounds__(TPB) void k_edt(const float* __restrict__ in,
                                             float* __restrict__ out) {
  int idx = blockIdx.x * TPB + threadIdx.x;     // over NT
  if (idx >= NT) return;
  int z, y, x; decomp(idx, z, y, x);
  int i, L, stride;
  if constexpr (AXIS == 0) { i = z; L = Dn; stride = HW; }
  else if constexpr (AXIS == 1) { i = y; L = Hn; stride = Wn; }
  else { i = x; L = Wn; stride = 1; }
  const float* __restrict__ p = in + (idx - i * stride);
  float fi = (float)i;
  float fj = 0.0f;
  float best = 3.4e38f;
  #pragma unroll 4
  for (int j = 0; j < L; ++j) {
    float d = fi - fj;                           // integer-valued, d*d exact
    best = fminf(best, fmaf(d, d, p[j * stride]));
    fj += 1.0f;
  }
  out[idx] = best;
}

// dist = sqrt(d2); d2==0 <=> mask==0, so reference's mask-zeroing is automatic
__global__ __launch_bounds__(TPB) void k_sqrt(float* __restrict__ a) {
  int idx = blockIdx.x * TPB + threadIdx.x;
  if (idx >= NT) return;
  a[idx] = sqrtf(a[idx]);
}

// per-(volume,batch) max of dist over skel==1 voxels; float-bits atomicMax (dist>=0)
__global__ __launch_bounds__(TPB) void k_rmax(const float* __restrict__ dist,
                                              const float* __restrict__ skel,
                                              unsigned* __restrict__ rmax) {
  __shared__ float red[TPB];
  int tid = threadIdx.x;
  int idx = blockIdx.x * TPB + tid;             // over NT
  float v = (skel[idx] == 1.0f) ? dist[idx] : 0.0f;
  red[tid] = v;
  __syncthreads();
  for (int off = TPB / 2; off > 0; off >>= 1) {
    if (tid < off) red[tid] = fmaxf(red[tid], red[tid + off]);
    __syncthreads();
  }
  if (tid == 0) {
    int vb = blockIdx.x / BLK_PER_VB;           // 0..3 = vol*B + b
    atomicMax(rmax + vb, __float_as_uint(red[0]));
  }
}

// per-voxel weighted terms, block-reduced in double, atomicAdd into 4 sums
__global__ __launch_bounds__(TPB) void k_sums(const float* __restrict__ dist,
                                              const float* __restrict__ skel,
                                              const unsigned* __restrict__ rmaxu,
                                              double* __restrict__ sums) {
  __shared__ double red[TPB];
  int tid = threadIdx.x;
  int idx = blockIdx.x * TPB + tid;             // over NBS
  int b = idx / S;
  float rmax_p = __uint_as_float(rmaxu[0 * Bn + b]);
  float rmax_t = __uint_as_float(rmaxu[1 * Bn + b]);
  float dist_p = dist[idx];
  float dist_t = dist[NBS + idx];
  bool sp = (skel[idx] == 1.0f);
  bool st = (skel[NBS + idx] == 1.0f);
  float q_vp = (rmax_p > 0.0f) ? dist_p / rmax_p : dist_p;
  float q_vl = (rmax_t > 0.0f) ? dist_t / rmax_t : dist_t;
  float q_spvp = sp ? q_vp : 0.0f;
  float q_slvl = st ? q_vl : 0.0f;
  float q_sp = sp ? (1.0f + EPSf) / (q_spvp * q_spvp + EPSf) : 0.0f;
  float q_sl = st ? (1.0f + EPSf) / (q_slvl * q_slvl + EPSf) : 0.0f;
  float t1 = q_sp * q_vl;
  float t2 = ((q_spvp != 0.0f) && (q_slvl == 0.0f)) ? q_spvp * q_sp : q_slvl * q_sp;
  float t3 = q_sl * q_vp;
  float t4 = ((q_slvl != 0.0f) && (q_spvp == 0.0f)) ? q_slvl * q_sl : q_spvp * q_sl;
  double terms[4] = {(double)t1, (double)t2, (double)t3, (double)t4};
  for (int k = 0; k < 4; ++k) {
    red[tid] = terms[k];
    __syncthreads();
    for (int off = TPB / 2; off > 0; off >>= 1) {
      if (tid < off) red[tid] += red[tid + off];
      __syncthreads();
    }
    if (tid == 0) atomicAdd(&sums[k], red[0]);
    __syncthreads();
  }
}

__global__ __launch_bounds__(64) void k_final(const double* __restrict__ sums,
                                              float* __restrict__ out) {
  if (threadIdx.x == 0) {
    double s1 = sums[0], s2 = sums[1], s3 = sums[2], s4 = sums[3];
    double wp = (s1 + 1.0) / (s2 + 1.0);
    double ws = (s3 + 1.0) / (s4 + 1.0);
    double loss = 1.0 - 2.0 * (wp * ws) / (wp + ws);
    out[0] = (float)loss;
  }
}

} // namespace

extern "C" void kernel_launch(void* const* d_in, const int* in_sizes, int n_in,
                              void* d_out, int out_size, void* d_ws, size_t ws_size,
                              hipStream_t stream) {
  (void)in_sizes; (void)n_in; (void)out_size; (void)ws_size;
  const float* logits = (const float*)d_in[0];   // [B,2,D,H,W] f32
  const int* labels   = (const int*)d_in[1];     // [B,1,D,H,W] i32
  float* out = (float*)d_out;

  // workspace layout: 5 stacked dual-volume float buffers + scalars
  float* M    = (float*)d_ws;          // masks, then reused as skeleton x / EDT ping-pong
  float* E    = M + NT;
  float* T    = E + NT;
  float* SKEL = T + NT;
  float* DIST = SKEL + NT;             // d2 init -> d2 passes -> dist
  double*   SUMS = (double*)(DIST + NT);   // byte offset 5*NT*4, 8-aligned
  unsigned* RMAX = (unsigned*)(SUMS + 4);

  dim3 blk(TPB);
  dim3 gNT(BLK_NT), gNBS(BLK_NBS);

  k_init_small<<<1, 64, 0, stream>>>(SUMS, RMAX);
  k_binarize<<<gNBS, blk, 0, stream>>>(logits, labels, M, DIST);

  // ---- soft skeleton (both volumes at once), buffer-rotating ----
  float *x = M, *e = E, *t = T;
  // skel = x && !open(x)
  k_erode<<<gNT, blk, 0, stream>>>(x, e);
  k_dil<0><<<gNT, blk, 0, stream>>>(e, t);
  k_dil<1><<<gNT, blk, 0, stream>>>(t, SKEL);    // SKEL used as temp pre-init
  k_dil<2><<<gNT, blk, 0, stream>>>(SKEL, t);
  k_skel_init<<<gNT, blk, 0, stream>>>(x, t, SKEL);
  for (int it = 0; it < NITER; ++it) {
    k_erode<<<gNT, blk, 0, stream>>>(x, e);      // e = x_new
    k_erode<<<gNT, blk, 0, stream>>>(e, t);      // t = erode(x_new)
    k_dil<0><<<gNT, blk, 0, stream>>>(t, x);     // old x dead -> reuse
    k_dil<1><<<gNT, blk, 0, stream>>>(x, t);
    k_dil<2><<<gNT, blk, 0, stream>>>(t, x);     // x = open(x_new)
    k_skel_upd<<<gNT, blk, 0, stream>>>(e, x, SKEL);
    float* tmp = x; x = e; e = tmp;              // x := x_new
  }

  // ---- exact EDT: 3 min-conv passes (d2 was initialized in k_binarize) ----
  k_edt<0><<<gNT, blk, 0, stream>>>(DIST, e);
  k_edt<1><<<gNT, blk, 0, stream>>>(e, t);
  k_edt<2><<<gNT, blk, 0, stream>>>(t, DIST);
  k_sqrt<<<gNT, blk, 0, stream>>>(DIST);

  // ---- weights + reductions ----
  k_rmax<<<gNT, blk, 0, stream>>>(DIST, SKEL, RMAX);
  k_sums<<<gNBS, blk, 0, stream>>>(DIST, SKEL, RMAX, SUMS);
  k_final<<<1, 64, 0, stream>>>(SUMS, out);
}

// Round 2
// 276.515 us; speedup vs baseline: 4.4758x; 4.4758x over previous
//
#include <hip/hip_runtime.h>

namespace {

constexpr int Bn = 2;
constexpr int Dn = 64;
constexpr int Hn = 96;
constexpr int Wn = 96;
constexpr int HW = Hn * Wn;          // 9216
constexpr int S  = Dn * HW;          // 589824 per (vol,batch) slab
constexpr int NBS = Bn * S;          // 1179648
constexpr int NT  = 2 * NBS;         // 2359296 (vol0=pred, vol1=truth)
constexpr int WPR = Wn / 32;         // 3 words per x-row
constexpr int WPP = HW / 32;         // 288 words per z-plane
constexpr int WPS = S / 32;          // 18432 words per slab
constexpr int NTW = NT / 32;         // 73728 packed words total
constexpr float INFD = 1e12f;
constexpr float EPSf = 1e-7f;
constexpr int TPB = 256;
constexpr int BLK_NT  = NT / TPB;    // 9216
constexpr int BLK_NBS = NBS / TPB;   // 4608
constexpr int BLK_W   = NTW / TPB;   // 288
constexpr int BLK_PER_VB = S / TPB;  // 2304 blocks per (vol,batch) in NT-kernels
constexpr int NITER = 10;

// ---- binarize both masks (bit-packed via ballot) + EDT d2 init (floats) ----
__global__ __launch_bounds__(TPB) void k_binarize(const float* __restrict__ logits,
                                                  const int* __restrict__ labels,
                                                  unsigned* __restrict__ Mb,
                                                  float* __restrict__ D2) {
  int idx = blockIdx.x * TPB + threadIdx.x;     // over NBS (exact multiple)
  int b = idx / S;
  int s = idx - b * S;
  float l0 = logits[(b * 2 + 0) * S + s];
  float l1 = logits[(b * 2 + 1) * S + s];
  bool vp = l1 > l0;                            // softmax(p1)>0.5 <=> l1>l0
  bool vt = labels[idx] > 0;
  D2[idx]       = vp ? INFD : 0.0f;
  D2[NBS + idx] = vt ? INFD : 0.0f;
  unsigned long long mp = __ballot(vp);
  unsigned long long mt = __ballot(vt);
  int lane = threadIdx.x & 63;
  if (lane == 0) {
    Mb[idx >> 5]         = (unsigned)mp;
    Mb[(NBS + idx) >> 5] = (unsigned)mt;        // NBS%32==0 -> word-aligned
  } else if (lane == 32) {
    Mb[idx >> 5]         = (unsigned)(mp >> 32);
    Mb[(NBS + idx) >> 5] = (unsigned)(mt >> 32);
  }
}

// ---- bit erode: AND of 7-point cross; OOB = 1 (minpool pads +inf) ----
__global__ __launch_bounds__(TPB) void k_erode_b(const unsigned* __restrict__ in,
                                                 unsigned* __restrict__ out) {
  int wi = blockIdx.x * TPB + threadIdx.x;      // over NTW (exact)
  int rw = wi % WPS;
  int z  = rw / WPP;
  int r2 = rw % WPP;
  int y  = r2 / WPR;
  int wx = r2 - y * WPR;
  unsigned v = in[wi];
  unsigned l = (v << 1) | (wx > 0       ? (in[wi - 1] >> 31) : 1u);
  unsigned r = (v >> 1) | (wx < WPR - 1 ? (in[wi + 1] << 31) : 0x80000000u);
  unsigned ym = (y > 0)      ? in[wi - WPR] : 0xFFFFFFFFu;
  unsigned yp = (y < Hn - 1) ? in[wi + WPR] : 0xFFFFFFFFu;
  unsigned zm = (z > 0)      ? in[wi - WPP] : 0xFFFFFFFFu;
  unsigned zp = (z < Dn - 1) ? in[wi + WPP] : 0xFFFFFFFFu;
  out[wi] = v & l & r & ym & yp & zm & zp;
}

// ---- fused 3x3x3 bit-dilate of t + skel update: skel (|)= xn & ~dilate(t) ----
template <bool INIT>
__global__ __launch_bounds__(TPB) void k_dil3_skel(const unsigned* __restrict__ xn,
                                                   const unsigned* __restrict__ t,
                                                   unsigned* __restrict__ skel) {
  int wi = blockIdx.x * TPB + threadIdx.x;
  int rw = wi % WPS;
  int z  = rw / WPP;
  int r2 = rw % WPP;
  int y  = r2 / WPR;
  int wx = r2 - y * WPR;
  unsigned acc = 0u;
  #pragma unroll
  for (int dz = -1; dz <= 1; ++dz) {
    if (z + dz < 0 || z + dz >= Dn) continue;
    #pragma unroll
    for (int dy = -1; dy <= 1; ++dy) {
      if (y + dy < 0 || y + dy >= Hn) continue;
      int base = wi + dz * WPP + dy * WPR;
      unsigned c = t[base];
      unsigned p = (wx > 0)       ? t[base - 1] : 0u;
      unsigned n = (wx < WPR - 1) ? t[base + 1] : 0u;
      acc |= c | ((c << 1) | (p >> 31)) | ((c >> 1) | (n << 31));
    }
  }
  unsigned d = xn[wi] & ~acc;
  if (INIT) skel[wi] = d;
  else      skel[wi] = skel[wi] | d;
}

// ---- EDT axis pass: out[i] = min_j (i-j)^2 + in[j]  (bitwise == reference) ----
template <int AXIS>
__global__ __launch_bounds__(TPB) void k_edt(const float* __restrict__ in,
                                             float* __restrict__ out) {
  int idx = blockIdx.x * TPB + threadIdx.x;     // over NT
  int s = idx % S;
  int z = s / HW;
  int r = s - z * HW;
  int y = r / Wn;
  int x = r - y * Wn;
  int i, L, stride;
  if constexpr (AXIS == 0)      { i = z; L = Dn; stride = HW; }
  else if constexpr (AXIS == 1) { i = y; L = Hn; stride = Wn; }
  else                          { i = x; L = Wn; stride = 1; }
  const float* __restrict__ p = in + (idx - i * stride);
  float fi = (float)i;
  float fj = 0.0f;
  float best = 3.4e38f;
  #pragma unroll 4
  for (int j = 0; j < L; ++j) {
    float d = fi - fj;                          // integer-valued -> d*d exact
    best = fminf(best, fmaf(d, d, p[j * stride]));
    fj += 1.0f;
  }
  out[idx] = best;
}

// ---- dist = sqrt(d2) in place + per-block skel-masked max (no atomics) ----
__global__ __launch_bounds__(TPB) void k_sqrt_rmax(float* __restrict__ d2,
                                                   const unsigned* __restrict__ skel,
                                                   float* __restrict__ pmax) {
  __shared__ float red[TPB];
  int tid = threadIdx.x;
  int idx = blockIdx.x * TPB + tid;             // over NT
  float d = sqrtf(d2[idx]);
  d2[idx] = d;
  bool on = (skel[idx >> 5] >> (idx & 31)) & 1u;
  red[tid] = on ? d : 0.0f;
  __syncthreads();
  for (int off = TPB / 2; off > 0; off >>= 1) {
    if (tid < off) red[tid] = fmaxf(red[tid], red[tid + off]);
    __syncthreads();
  }
  if (tid == 0) pmax[blockIdx.x] = red[0];
}

// ---- stage 2: per-(vol,batch) max of 2304 block partials ----
__global__ __launch_bounds__(TPB) void k_rmax2(const float* __restrict__ pmax,
                                               float* __restrict__ rmaxf) {
  __shared__ float red[TPB];
  int tid = threadIdx.x;
  float m = 0.0f;
  const float* p = pmax + blockIdx.x * BLK_PER_VB;
  for (int i = tid; i < BLK_PER_VB; i += TPB) m = fmaxf(m, p[i]);
  red[tid] = m;
  __syncthreads();
  for (int off = TPB / 2; off > 0; off >>= 1) {
    if (tid < off) red[tid] = fmaxf(red[tid], red[tid + off]);
    __syncthreads();
  }
  if (tid == 0) rmaxf[blockIdx.x] = red[0];
}

// ---- per-voxel weighted terms -> per-block double4 partials (no atomics) ----
__global__ __launch_bounds__(TPB) void k_sums1(const float* __restrict__ dist,
                                               const unsigned* __restrict__ skel,
                                               const float* __restrict__ rmaxf,
                                               double* __restrict__ ps) {
  __shared__ double red[TPB];
  int tid = threadIdx.x;
  int idx = blockIdx.x * TPB + tid;             // over NBS
  int b = idx / S;
  float rmax_p = rmaxf[0 * Bn + b];
  float rmax_t = rmaxf[1 * Bn + b];
  float dist_p = dist[idx];
  float dist_t = dist[NBS + idx];
  bool sp = (skel[idx >> 5] >> (idx & 31)) & 1u;
  bool st = (skel[(NBS + idx) >> 5] >> (idx & 31)) & 1u;
  float q_vp = (rmax_p > 0.0f) ? dist_p / rmax_p : dist_p;
  float q_vl = (rmax_t > 0.0f) ? dist_t / rmax_t : dist_t;
  float q_spvp = sp ? q_vp : 0.0f;
  float q_slvl = st ? q_vl : 0.0f;
  float q_sp = sp ? (1.0f + EPSf) / (q_spvp * q_spvp + EPSf) : 0.0f;
  float q_sl = st ? (1.0f + EPSf) / (q_slvl * q_slvl + EPSf) : 0.0f;
  float t1 = q_sp * q_vl;
  float t2 = ((q_spvp != 0.0f) && (q_slvl == 0.0f)) ? q_spvp * q_sp : q_slvl * q_sp;
  float t3 = q_sl * q_vp;
  float t4 = ((q_slvl != 0.0f) && (q_spvp == 0.0f)) ? q_slvl * q_sl : q_spvp * q_sl;
  double terms[4] = {(double)t1, (double)t2, (double)t3, (double)t4};
  #pragma unroll
  for (int k = 0; k < 4; ++k) {
    red[tid] = terms[k];
    __syncthreads();
    for (int off = TPB / 2; off > 0; off >>= 1) {
      if (tid < off) red[tid] += red[tid + off];
      __syncthreads();
    }
    if (tid == 0) ps[blockIdx.x * 4 + k] = red[0];
    __syncthreads();
  }
}

// ---- stage 2: reduce 4608 partials per term, compute loss ----
__global__ __launch_bounds__(TPB) void k_sums2(const double* __restrict__ ps,
                                               float* __restrict__ out) {
  __shared__ double red[TPB];
  int tid = threadIdx.x;
  double s[4] = {0.0, 0.0, 0.0, 0.0};
  for (int i = tid; i < BLK_NBS; i += TPB) {
    s[0] += ps[i * 4 + 0];
    s[1] += ps[i * 4 + 1];
    s[2] += ps[i * 4 + 2];
    s[3] += ps[i * 4 + 3];
  }
  double tot[4];
  #pragma unroll
  for (int k = 0; k < 4; ++k) {
    red[tid] = s[k];
    __syncthreads();
    for (int off = TPB / 2; off > 0; off >>= 1) {
      if (tid < off) red[tid] += red[tid + off];
      __syncthreads();
    }
    if (tid == 0) tot[k] = red[0];
    __syncthreads();
  }
  if (tid == 0) {
    double wp = (tot[0] + 1.0) / (tot[1] + 1.0);
    double ws = (tot[2] + 1.0) / (tot[3] + 1.0);
    out[0] = (float)(1.0 - 2.0 * (wp * ws) / (wp + ws));
  }
}

} // namespace

extern "C" void kernel_launch(void* const* d_in, const int* in_sizes, int n_in,
                              void* d_out, int out_size, void* d_ws, size_t ws_size,
                              hipStream_t stream) {
  (void)in_sizes; (void)n_in; (void)out_size; (void)ws_size;
  const float* logits = (const float*)d_in[0];   // [B,2,D,H,W] f32
  const int* labels   = (const int*)d_in[1];     // [B,1,D,H,W] i32
  float* out = (float*)d_out;

  // workspace layout (all offsets 8B-aligned): 3 float volumes, 4 packed, partials
  float* D2 = (float*)d_ws;            // d2 init -> EDT ping-pong -> dist
  float* EF = D2 + NT;
  float* TF = EF + NT;
  unsigned* XB    = (unsigned*)(TF + NT);
  unsigned* EB    = XB + NTW;
  unsigned* TBb   = EB + NTW;
  unsigned* SKELB = TBb + NTW;
  float* PMAX  = (float*)(SKELB + NTW);   // 9216 per-block maxes
  double* PS   = (double*)(PMAX + BLK_NT);// 4608*4 doubles (offset multiple of 8)
  float* RMAXF = (float*)(PS + 4 * BLK_NBS); // 4 floats

  dim3 blk(TPB);

  k_binarize<<<BLK_NBS, blk, 0, stream>>>(logits, labels, XB, D2);

  // ---- soft skeleton, bit-packed; 2 dispatches per iteration ----
  // init: skel = x & ~dil3(erode(x))
  k_erode_b<<<BLK_W, blk, 0, stream>>>(XB, EB);            // er = erode(x0)
  k_dil3_skel<true><<<BLK_W, blk, 0, stream>>>(XB, EB, SKELB);
  unsigned *cur = XB, *er = EB, *tmp = TBb;
  for (int it = 0; it < NITER; ++it) {
    // reference: x = erode(x)  -> that's exactly `er` from the previous step
    unsigned* xnew = er;
    k_erode_b<<<BLK_W, blk, 0, stream>>>(xnew, tmp);       // tmp = erode(x_new)
    k_dil3_skel<false><<<BLK_W, blk, 0, stream>>>(xnew, tmp, SKELB);
    // rotate: next iter's erode(x) is `tmp`; old `cur` becomes scratch
    unsigned* old_cur = cur;
    cur = xnew; er = tmp; tmp = old_cur;
  }

  // ---- exact EDT: 3 brute-force min-conv passes ----
  k_edt<0><<<BLK_NT, blk, 0, stream>>>(D2, EF);
  k_edt<1><<<BLK_NT, blk, 0, stream>>>(EF, TF);
  k_edt<2><<<BLK_NT, blk, 0, stream>>>(TF, D2);

  // ---- sqrt + rmax (two-stage, deterministic) ----
  k_sqrt_rmax<<<BLK_NT, blk, 0, stream>>>(D2, SKELB, PMAX);
  k_rmax2<<<4, blk, 0, stream>>>(PMAX, RMAXF);

  // ---- weighted sums (two-stage, no atomics) + loss ----
  k_sums1<<<BLK_NBS, blk, 0, stream>>>(D2, SKELB, RMAXF, PS);
  k_sums2<<<1, blk, 0, stream>>>(PS, out);
}